// Round 7
// baseline (729.821 us; speedup 1.0000x reference)
//
#include <hip/hip_runtime.h>
#include <math.h>

// Sinkhorn regularized transport, B=8, m=n=1024, fp32, 100 iterations.
//
// Round 7 = R4 comm skeleton with the owner-reduce/broadcast replaced by an
// L3 atomicAdd all-reduce (half the protocol deleted).
//
// Evidence trail:
//  R1: atomicAdd reduce + fence-barrier = 13us/iter, of which ~12us was the
//      fence-barrier -> atomics themselves are cheap (<1us for 262K adds).
//  R4: stamp-flag protocol = 5.3us/iter; chain = partial store+drain+stampA+
//      poll+8KB rw + v publish+drain+stampV+poll+4KB read (~5 RTTs).
//  R5: lesson - polls must hit one dedicated flag line (packed-data polling
//      streamed at HBM, 886MB writes).
//  R6: register-K neutral (AGPR moves ate the LDS savings); LDS compute is
//      not the critical path - the serialized comm chain is.
// This round: phase A atomicAdds partials straight into per-batch y[it%3]
// (device-scope fp32 RMW at L3); __syncthreads drains the acks (vmcnt 0);
// one stamp publish + one poll; then every block reads the completed 4KB y
// and computes v=c/y locally (bit-identical everywhere). Triple-buffered y,
// in-loop zeroing of buffer (it+2)%3: those zero stores drain under the NEXT
// iteration's vmcnt(0) before stampA(it+2) is published, and all readers of
// that buffer (as (it-1)%3) are provably done once poll(it+1) passes.

#define B_    8
#define N_    1024
#define G_    32          // blocks per batch
#define RPB   32          // rows per block
#define KSTR  1028        // LDS row stride (floats): 16B aligned, bank skew
#define NITER 100
#define TPB   256
#define LMB   10.0f
#define MAXD  5.0f

// LDS: Kl (RPB*KSTR) + vl (N_) + ul (RPB)
#define LDS_FLOATS (RPB * KSTR + N_ + RPB)

typedef unsigned long long u64;

__device__ __forceinline__ void st8(float* p, float a, float b) {
    float2 f2 = make_float2(a, b);
    __hip_atomic_store((u64*)p, __builtin_bit_cast(u64, f2),
                       __ATOMIC_RELAXED, __HIP_MEMORY_SCOPE_AGENT);
}
__device__ __forceinline__ float2 ld8(const float* p) {
    u64 raw = __hip_atomic_load((const u64*)p,
                                __ATOMIC_RELAXED, __HIP_MEMORY_SCOPE_AGENT);
    return __builtin_bit_cast(float2, raw);
}
__device__ __forceinline__ void publish(int* s, int v) {
    __atomic_signal_fence(__ATOMIC_SEQ_CST);
    __hip_atomic_store(s, v, __ATOMIC_RELAXED, __HIP_MEMORY_SCOPE_AGENT);
}
// Wait until all 32 stamps reach tgt: one coalesced 128B flag line per poll.
__device__ __forceinline__ void poll32(const int* st, int tgt) {
    const int l = threadIdx.x & 31;
    for (;;) {
        int s = __hip_atomic_load(&st[l], __ATOMIC_RELAXED,
                                  __HIP_MEMORY_SCOPE_AGENT);
        if (__all(s >= tgt)) break;
        __builtin_amdgcn_s_sleep(1);
    }
    __atomic_signal_fence(__ATOMIC_SEQ_CST);
}

__global__ void __launch_bounds__(TPB, 1)
sinkhorn_kernel(const float* __restrict__ Mg,
                float* __restrict__ Pg,
                float* __restrict__ ybufs,   // [3][B_][N_]
                int* __restrict__ stA)       // [B_][G_] monotonic stamps
{
    extern __shared__ float lds[];
    float* Kl = lds;                    // RPB x KSTR
    float* vl = lds + RPB * KSTR;       // N_
    float* ul = vl + N_;                // RPB

    const int b    = blockIdx.x & (B_ - 1);
    const int g    = blockIdx.x >> 3;
    const int t    = threadIdx.x;
    const int row0 = g * RPB;
    const float r = 1.0f / (float)N_;
    const float c = 1.0f / (float)N_;

    // ---- stage K rows into LDS ----
    const float* Mb = Mg + ((size_t)b * N_ + row0) * N_;
    for (int i = 0; i < RPB; ++i) {
        float4 m4 = ((const float4*)(Mb + (size_t)i * N_))[t];
        float4 k4;
        k4.x = expf(-LMB * fminf(m4.x, MAXD));
        k4.y = expf(-LMB * fminf(m4.y, MAXD));
        k4.z = expf(-LMB * fminf(m4.z, MAXD));
        k4.w = expf(-LMB * fminf(m4.w, MAXD));
        *(float4*)&Kl[i * KSTR + 4 * t] = k4;
    }
    if (t < RPB) ul[t] = r;             // u = r initially
    __syncthreads();

    int* stA_b = stA + b * G_;

    for (int it = 0; it <= NITER; ++it) {
        float* ym  = ybufs + ((size_t)(it % 3) * B_ + b) * N_;
        float* yz  = ybufs + ((size_t)((it + 2) % 3) * B_ + b) * N_;
        const int tgt = it + 1;

        // ---- phase A: y[j] += sum_{own rows i} K[i][j] * u_i (L3 RMW) ----
        float4 a = make_float4(0.f, 0.f, 0.f, 0.f);
#pragma unroll
        for (int i = 0; i < RPB; ++i) {
            const float u  = ul[i];
            const float4 k4 = *(const float4*)&Kl[i * KSTR + 4 * t];
            a.x = fmaf(k4.x, u, a.x);
            a.y = fmaf(k4.y, u, a.y);
            a.z = fmaf(k4.z, u, a.z);
            a.w = fmaf(k4.w, u, a.w);
        }
        atomicAdd(&ym[4 * t + 0], a.x);
        atomicAdd(&ym[4 * t + 1], a.y);
        atomicAdd(&ym[4 * t + 2], a.z);
        atomicAdd(&ym[4 * t + 3], a.w);

        __syncthreads();                     // vmcnt(0): all adds acked at L3
        if (t == 0) publish(&stA_b[g], tgt);

        poll32(stA_b, tgt);                  // all 32 blocks' adds complete

        // zero buffer (it+2)%3, own 32-col slice (drains under next iter's
        // vmcnt(0) before stampA(it+2); readers proven past it by this poll)
        if (t < 16) st8(&yz[32 * g + 2 * t], 0.f, 0.f);

        // ---- read completed y, v = c/y (bit-identical in every block) ----
        {
            float2 w0 = ld8(&ym[4 * t]);
            float2 w1 = ld8(&ym[4 * t + 2]);
            *(float4*)&vl[4 * t] =
                make_float4(c / w0.x, c / w0.y, c / w1.x, c / w1.y);
        }
        __syncthreads();

        if (it == NITER) break;              // vl holds final v

        // ---- phase B: z_i = sum_j K[i][j] v_j ; u_i = r / z_i ----
        const int rI = t >> 3;               // 0..31 (row within block)
        const int l  = t & 7;                // 0..7  (8 lanes per row)
        float4 za = make_float4(0.f, 0.f, 0.f, 0.f);
#pragma unroll
        for (int k2 = 0; k2 < 32; ++k2) {
            const int j0 = 4 * l + 32 * k2;
            const float4 k4 = *(const float4*)&Kl[rI * KSTR + j0];
            const float4 vv = *(const float4*)&vl[j0];
            za.x = fmaf(k4.x, vv.x, za.x);
            za.y = fmaf(k4.y, vv.y, za.y);
            za.z = fmaf(k4.z, vv.z, za.z);
            za.w = fmaf(k4.w, vv.w, za.w);
        }
        float z = za.x + za.y + za.z + za.w;
        z += __shfl_xor(z, 1);
        z += __shfl_xor(z, 2);
        z += __shfl_xor(z, 4);
        if (l == 0) ul[rI] = r / z;
        __syncthreads();
    }

    // ---- epilogue: P[i][j] = u_i * K[i][j] * v_j ----
    float* Pb = Pg + ((size_t)b * N_ + row0) * N_;
    const float4 v4 = *(const float4*)&vl[4 * t];
    for (int i = 0; i < RPB; ++i) {
        const float u  = ul[i];
        const float4 k4 = *(const float4*)&Kl[i * KSTR + 4 * t];
        float4 p4;
        p4.x = u * k4.x * v4.x;
        p4.y = u * k4.y * v4.y;
        p4.z = u * k4.z * v4.z;
        p4.w = u * k4.w * v4.w;
        ((float4*)(Pb + (size_t)i * N_))[t] = p4;
    }
}

extern "C" void kernel_launch(void* const* d_in, const int* in_sizes, int n_in,
                              void* d_out, int out_size, void* d_ws, size_t ws_size,
                              hipStream_t stream) {
    const float* M = (const float*)d_in[0];
    float* P = (float*)d_out;

    const size_t y_floats = (size_t)3 * B_ * N_;           // 96 KB
    float* ybufs = (float*)d_ws;
    int*   stA   = (int*)(ybufs + y_floats);
    // y buffers must start at zero (first three iterations); stamps at 0.
    hipMemsetAsync(d_ws, 0,
                   y_floats * sizeof(float) + (size_t)B_ * G_ * sizeof(int),
                   stream);

    const size_t lds_bytes = (size_t)LDS_FLOATS * sizeof(float);
    (void)hipFuncSetAttribute((const void*)sinkhorn_kernel,
                              hipFuncAttributeMaxDynamicSharedMemorySize,
                              (int)lds_bytes);

    void* args[] = { (void*)&M, (void*)&P, (void*)&ybufs, (void*)&stA };
    hipError_t e = hipLaunchCooperativeKernel((void*)sinkhorn_kernel,
                                              dim3(B_ * G_), dim3(TPB),
                                              args, (unsigned)lds_bytes, stream);
    if (e != hipSuccess) {
        // fallback: 256 blocks at 1 block/CU on 256 CUs is co-resident,
        // which the stamp-flag dataflow requires
        sinkhorn_kernel<<<dim3(B_ * G_), dim3(TPB), lds_bytes, stream>>>(
            M, P, ybufs, stA);
    }
}